// Round 1
// baseline (502.225 us; speedup 1.0000x reference)
//
#include <hip/hip_runtime.h>

#define HW 3136
#define NC 128
#define NO 128
#define NB 64

typedef __attribute__((ext_vector_type(4))) float f32x4;
typedef __attribute__((ext_vector_type(8))) short s16x8;
typedef __attribute__((ext_vector_type(8))) __bf16 bf16x8;
typedef unsigned long long ull;
typedef __attribute__((ext_vector_type(2))) ull u64x2;

// ws layout (bytes)
#define XLEV_BYTES (25690112UL * 2UL)
#define WLEV_OFF   XLEV_BYTES
#define WLEV_BYTES (589824UL * 2UL)
#define POOL_OFF   (WLEV_OFF + WLEV_BYTES)
#define POOL_BYTES (8192UL * 8UL)
#define PAR_OFF    (POOL_OFF + POOL_BYTES)

__device__ __forceinline__ unsigned short f2bf_bits(float f) {
    // values are exact small integers -> truncation of top 16 bits is exact
    return (unsigned short)(__float_as_uint(f) >> 16);
}

// ---------------- pool: pooled[b][c] = mean_{h,w} x  (f64 accumulate) ----------------
__global__ void pool_kernel(const float* __restrict__ x, double* __restrict__ pooled) {
    int row = blockIdx.x * 4 + (threadIdx.x >> 6); // (b*128+c), 8192 rows
    int lane = threadIdx.x & 63;
    const float4* xr = (const float4*)(x + (size_t)row * HW);
    double s = 0.0;
    for (int i = lane; i < 784; i += 64) {
        float4 v = xr[i];
        s += (double)v.x + (double)v.y + (double)v.z + (double)v.w;
    }
    for (int off = 32; off; off >>= 1) s += __shfl_down(s, off, 64);
    if (lane == 0) pooled[row] = s / 3136.0;
}

// ---------------- gate: fc1->relu->fc2->softmax/argmax -> per-batch params ----------------
__global__ void gate_kernel(const double* __restrict__ pooled,
                            const float* __restrict__ fc1, const float* __restrict__ fc2,
                            const float* __restrict__ fc2b, const float* __restrict__ alpha_w,
                            const float* __restrict__ alpha_a,
                            float* __restrict__ params, float* __restrict__ raw_out) {
    __shared__ double pl[8192]; // transposed [c][b] to avoid bank conflicts
    int t = threadIdx.x; // 64 threads
    for (int i = t; i < 8192; i += 64) {
        int b = i >> 7, c = i & 127;
        pl[c * 64 + b] = pooled[i];
    }
    __syncthreads();
    int b = t;
    double h[33];
    for (int j = 0; j < 33; j++) {
        double s = 0.0;
        for (int c = 0; c < 128; c++) s += pl[c * 64 + b] * (double)fc1[j * 128 + c];
        h[j] = s > 0.0 ? s : 0.0;
    }
    float raw[4];
    for (int k = 0; k < 4; k++) {
        double s = (double)fc2b[k];
        for (int j = 0; j < 33; j++) s += h[j] * (double)fc2[k * 33 + j];
        raw[k] = (float)s;
        raw_out[b * 4 + k] = raw[k];
    }
    int kb = 0; float mx = raw[0];
    for (int k = 1; k < 4; k++) if (raw[k] > mx) { mx = raw[k]; kb = k; }
    // replicate np f32 softmax (with max subtraction), exp via correctly-rounded f64
    float z[4], m = -1e30f;
    for (int k = 0; k < 4; k++) { z[k] = __fdiv_rn(raw[k], 34.0f); m = fmaxf(m, z[k]); }
    float p[4], sum = 0.0f;
    for (int k = 0; k < 4; k++) {
        p[k] = (float)exp((double)__fsub_rn(z[k], m));
        sum = __fadd_rn(sum, p[k]);
    }
    float s_k   = __fdiv_rn(p[kb], sum);
    float attn1 = __fadd_rn(__fsub_rn(1.0f, s_k), s_k);  // forward value of attn at argmax
    float Qp    = (float)((1 << (kb + 2)) - 1);
    float rQp   = __fmul_rn(attn1, Qp);
    float r_al  = __fmul_rn(attn1, alpha_a[kb]);
    float g_a   = __fdiv_rn(1.0f, __fsqrt_rn(__fmul_rn(401408.0f, rQp)));
    float ta    = __fmul_rn(r_al, g_a);
    float a     = __fadd_rn(__fsub_rn(r_al, ta), ta);
    float Qpw   = (float)((1 << (kb + 1)) - 1);
    float g_w   = __fdiv_rn(1.0f, __fsqrt_rn(__fmul_rn(589824.0f, Qpw)));
    float tw    = __fmul_rn(alpha_w[kb], g_w);
    float aw    = __fadd_rn(__fsub_rn(alpha_w[kb], tw), tw);
    params[b * 8 + 0] = __int_as_float(kb);
    params[b * 8 + 1] = a;
    params[b * 8 + 2] = rQp;
    params[b * 8 + 3] = attn1;
    params[b * 8 + 4] = __fmul_rn(a, aw);
}

// ---------------- weight quant -> swizzled bf16 levels [k][tap][cb][o][c'] ----------------
__global__ void wq_kernel(const float* __restrict__ w, const float* __restrict__ alpha_w,
                          unsigned short* __restrict__ wlev) {
    int idx = blockIdx.x * 256 + threadIdx.x; // 589824 = 4*128*128*9
    int tap = idx % 9; int rest = idx / 9;
    int c = rest % 128; rest /= 128;
    int o = rest % 128; int k = rest / 128;
    float Qpw = (float)((1 << (k + 1)) - 1);
    float Qnw = -(float)(1 << (k + 1));
    float g_w = __fdiv_rn(1.0f, __fsqrt_rn(__fmul_rn(589824.0f, Qpw)));
    float tw  = __fmul_rn(alpha_w[k], g_w);
    float aw  = __fadd_rn(__fsub_rn(alpha_w[k], tw), tw);
    float lv  = rintf(fminf(fmaxf(__fdiv_rn(w[idx], aw), Qnw), Qpw));
    size_t dst = ((((size_t)k * 9 + tap) * 4 + (c >> 5)) * 128 + o) * 32 + (c & 31);
    wlev[dst] = f2bf_bits(lv);
}

// ---------------- x quant + transpose -> bf16 levels [b][p][c] ----------------
__global__ void xq_kernel(const float* __restrict__ x, const float* __restrict__ params,
                          unsigned short* __restrict__ xlev) {
    __shared__ unsigned short lds[64 * 136]; // 64 pixels x 128 c, padded rows (272B, 16B-aligned)
    int b = blockIdx.y, tile = blockIdx.x;
    int p0 = tile * 64;
    float a = params[b * 8 + 1], rQp = params[b * 8 + 2];
    const float* xb = x + (size_t)b * 401408;
    int t = threadIdx.x;
    int cc = t >> 4;          // 0..15
    int p4 = (t & 15) * 4;    // 0..60
    for (int j = 0; j < 8; j++) {
        int c = cc * 8 + j;
        float4 v = *(const float4*)(xb + (size_t)c * HW + p0 + p4);
        float q0 = rintf(fminf(fmaxf(__fdiv_rn(v.x, a), 0.0f), rQp));
        float q1 = rintf(fminf(fmaxf(__fdiv_rn(v.y, a), 0.0f), rQp));
        float q2 = rintf(fminf(fmaxf(__fdiv_rn(v.z, a), 0.0f), rQp));
        float q3 = rintf(fminf(fmaxf(__fdiv_rn(v.w, a), 0.0f), rQp));
        lds[(p4 + 0) * 136 + c] = f2bf_bits(q0);
        lds[(p4 + 1) * 136 + c] = f2bf_bits(q1);
        lds[(p4 + 2) * 136 + c] = f2bf_bits(q2);
        lds[(p4 + 3) * 136 + c] = f2bf_bits(q3);
    }
    __syncthreads();
    int p = t >> 2, seg = t & 3;
    u64x2* dst = (u64x2*)(xlev + (size_t)b * 401408 + (size_t)(p0 + p) * 128 + seg * 32);
    const unsigned short* s = &lds[p * 136 + seg * 32];
    dst[0] = *(const u64x2*)(s);
    dst[1] = *(const u64x2*)(s + 8);
    dst[2] = *(const u64x2*)(s + 16);
    dst[3] = *(const u64x2*)(s + 24);
}

// ---------------- conv: implicit GEMM, 128x128 block tile, bf16 MFMA on integer levels ----------------
__launch_bounds__(256)
__global__ void conv_kernel(const unsigned short* __restrict__ xlev,
                            const unsigned short* __restrict__ wlev,
                            const float* __restrict__ params,
                            const float* __restrict__ bias,
                            float* __restrict__ out) {
    __shared__ unsigned short Alds[128 * 40]; // weights [o][c'], rows 80B (16B-aligned, conflict-free b128)
    __shared__ unsigned short Blds[128 * 40]; // x levels [p][c']
    int b = blockIdx.y;
    int tile = blockIdx.x;  // 0..24 (25 tiles of 128 pixels; last half-masked)
    int p0 = tile * 128;
    int kb = __float_as_int(params[b * 8 + 0]);
    float scale = params[b * 8 + 4], attn1 = params[b * 8 + 3];
    const unsigned short* xb = xlev + (size_t)b * 401408;
    const unsigned short* wb = wlev + (size_t)kb * 9 * 4 * 4096;
    int tid = threadIdx.x;
    int lane = tid & 63, wv = tid >> 6;
    int wm = wv & 1, wn = wv >> 1;
    int q = lane >> 4, l16 = lane & 15;

    f32x4 acc[4][4] = {};

    int c8  = (tid & 3) * 8;
    int pB0 = tid >> 2, pB1 = (tid >> 2) + 64;
    int pf0 = p0 + pB0, pf1 = p0 + pB1;
    int h0 = pf0 / 56, w0 = pf0 - h0 * 56;
    int h1 = pf1 / 56, w1 = pf1 - h1 * 56;

    for (int t9 = 0; t9 < 9; t9++) {
        int dh = t9 / 3 - 1, dw = t9 % 3 - 1;
        int shift = dh * 56 + dw;
        bool v0 = (pf0 < 3136) && ((unsigned)(h0 + dh) < 56u) && ((unsigned)(w0 + dw) < 56u);
        bool v1 = (pf1 < 3136) && ((unsigned)(h1 + dh) < 56u) && ((unsigned)(w1 + dw) < 56u);
        const unsigned short* wt = wb + t9 * 4 * 4096;
        for (int cb = 0; cb < 4; cb++) {
            // stage A (8KB): [o][c'] already pre-swizzled contiguous in global
            const u64x2* ga = (const u64x2*)(wt + cb * 4096);
            u64x2 va0 = ga[tid];
            u64x2 va1 = ga[tid + 256];
            // stage B (8KB) with zero-padding mask
            int c0 = cb * 32;
            u64x2 vb0 = {0, 0}, vb1 = {0, 0};
            if (v0) vb0 = *(const u64x2*)(xb + (size_t)(pf0 + shift) * 128 + c0 + c8);
            if (v1) vb1 = *(const u64x2*)(xb + (size_t)(pf1 + shift) * 128 + c0 + c8);
            *(u64x2*)(&Alds[(tid >> 2) * 40 + c8])        = va0;
            *(u64x2*)(&Alds[((tid >> 2) + 64) * 40 + c8]) = va1;
            *(u64x2*)(&Blds[pB0 * 40 + c8]) = vb0;
            *(u64x2*)(&Blds[pB1 * 40 + c8]) = vb1;
            __syncthreads();
            s16x8 af[4], bf[4];
            for (int mt = 0; mt < 4; mt++)
                af[mt] = *(const s16x8*)(&Alds[(wm * 64 + mt * 16 + l16) * 40 + q * 8]);
            for (int nt = 0; nt < 4; nt++)
                bf[nt] = *(const s16x8*)(&Blds[(wn * 64 + nt * 16 + l16) * 40 + q * 8]);
            for (int mt = 0; mt < 4; mt++)
                for (int nt = 0; nt < 4; nt++)
                    acc[mt][nt] = __builtin_amdgcn_mfma_f32_16x16x32_bf16(
                        __builtin_bit_cast(bf16x8, af[mt]),
                        __builtin_bit_cast(bf16x8, bf[nt]),
                        acc[mt][nt], 0, 0, 0);
            __syncthreads();
        }
    }
    // epilogue: out = fl(scale*acc_int) + fl(attn1*bias)
    const float* bias_k = bias + kb * 128;
    for (int mt = 0; mt < 4; mt++) {
        for (int r = 0; r < 4; r++) {
            int o = wm * 64 + mt * 16 + q * 4 + r;
            float bt = __fmul_rn(attn1, bias_k[o]);
            float* orow = out + ((size_t)b * 128 + o) * 3136;
            for (int nt = 0; nt < 4; nt++) {
                int pf = p0 + wn * 64 + nt * 16 + l16;
                if (pf < 3136)
                    orow[pf] = __fadd_rn(__fmul_rn(scale, acc[mt][nt][r]), bt);
            }
        }
    }
}

extern "C" void kernel_launch(void* const* d_in, const int* in_sizes, int n_in,
                              void* d_out, int out_size, void* d_ws, size_t ws_size,
                              hipStream_t stream) {
    const float* x        = (const float*)d_in[0];
    const float* fc1_w    = (const float*)d_in[1];
    const float* fc2_w    = (const float*)d_in[2];
    const float* fc2_b    = (const float*)d_in[3];
    const float* alpha_w  = (const float*)d_in[4];
    const float* alpha_a  = (const float*)d_in[5];
    const float* weight   = (const float*)d_in[6];
    const float* bias     = (const float*)d_in[7];
    float* out = (float*)d_out;

    char* ws = (char*)d_ws;
    unsigned short* xlev = (unsigned short*)(ws);
    unsigned short* wlev = (unsigned short*)(ws + WLEV_OFF);
    double* pooled       = (double*)(ws + POOL_OFF);
    float* par           = (float*)(ws + PAR_OFF);

    hipLaunchKernelGGL(pool_kernel, dim3(2048), dim3(256), 0, stream, x, pooled);
    hipLaunchKernelGGL(gate_kernel, dim3(1), dim3(64), 0, stream,
                       pooled, fc1_w, fc2_w, fc2_b, alpha_w, alpha_a, par, out + 25690112);
    hipLaunchKernelGGL(wq_kernel, dim3(2304), dim3(256), 0, stream, weight, alpha_w, wlev);
    hipLaunchKernelGGL(xq_kernel, dim3(49, 64), dim3(256), 0, stream, x, par, xlev);
    hipLaunchKernelGGL(conv_kernel, dim3(25, 64), dim3(256), 0, stream, xlev, wlev, par, bias, out);
}

// Round 2
// 314.419 us; speedup vs baseline: 1.5973x; 1.5973x over previous
//
#include <hip/hip_runtime.h>

#define HW 3136
#define NC 128
#define NO 128
#define NB 64

typedef __attribute__((ext_vector_type(4))) float f32x4;
typedef __attribute__((ext_vector_type(8))) short s16x8;
typedef __attribute__((ext_vector_type(8))) __bf16 bf16x8;
typedef unsigned long long ull;
typedef __attribute__((ext_vector_type(2))) ull u64x2;

// ws layout (bytes)
#define XLEV_BYTES (25690112UL * 2UL)
#define WLEV_OFF   XLEV_BYTES
#define WLEV_BYTES (589824UL * 2UL)
#define POOL_OFF   (WLEV_OFF + WLEV_BYTES)
#define POOL_BYTES (8192UL * 8UL)
#define PAR_OFF    (POOL_OFF + POOL_BYTES)

__device__ __forceinline__ unsigned short f2bf_bits(float f) {
    // values are exact small integers -> truncation of top 16 bits is exact
    return (unsigned short)(__float_as_uint(f) >> 16);
}

// ---------------- pool: pooled[b][c] = mean_{h,w} x  (f64 accumulate) ----------------
__global__ void pool_kernel(const float* __restrict__ x, double* __restrict__ pooled) {
    int row = blockIdx.x * 4 + (threadIdx.x >> 6); // (b*128+c), 8192 rows
    int lane = threadIdx.x & 63;
    const float4* xr = (const float4*)(x + (size_t)row * HW);
    double s = 0.0;
    for (int i = lane; i < 784; i += 64) {
        float4 v = xr[i];
        s += (double)v.x + (double)v.y + (double)v.z + (double)v.w;
    }
    for (int off = 32; off; off >>= 1) s += __shfl_down(s, off, 64);
    if (lane == 0) pooled[row] = s / 3136.0;
}

// ---------------- gate: 64 blocks (one per batch), 64 threads ----------------
// Thread j computes h[j] with the same serial c-order as before (bitwise-identical).
__global__ void gate_kernel(const double* __restrict__ pooled,
                            const float* __restrict__ fc1, const float* __restrict__ fc2,
                            const float* __restrict__ fc2b, const float* __restrict__ alpha_w,
                            const float* __restrict__ alpha_a,
                            float* __restrict__ params, float* __restrict__ raw_out) {
    int b = blockIdx.x;
    int t = threadIdx.x; // 64
    __shared__ double pl[128];
    __shared__ double hsh[33];
    __shared__ float rawsh[4];
    pl[t]      = pooled[b * 128 + t];
    pl[t + 64] = pooled[b * 128 + 64 + t];
    __syncthreads();
    if (t < 33) {
        double s = 0.0;
        for (int c = 0; c < 128; c++) s += pl[c] * (double)fc1[t * 128 + c];
        hsh[t] = s > 0.0 ? s : 0.0;
    }
    __syncthreads();
    if (t < 4) {
        double s = (double)fc2b[t];
        for (int j = 0; j < 33; j++) s += hsh[j] * (double)fc2[t * 33 + j];
        float r = (float)s;
        rawsh[t] = r;
        raw_out[b * 4 + t] = r;
    }
    __syncthreads();
    if (t == 0) {
        float raw[4];
        for (int k = 0; k < 4; k++) raw[k] = rawsh[k];
        int kb = 0; float mx = raw[0];
        for (int k = 1; k < 4; k++) if (raw[k] > mx) { mx = raw[k]; kb = k; }
        // replicate np f32 softmax (with max subtraction), exp via correctly-rounded f64
        float z[4], m = -1e30f;
        for (int k = 0; k < 4; k++) { z[k] = __fdiv_rn(raw[k], 34.0f); m = fmaxf(m, z[k]); }
        float p[4], sum = 0.0f;
        for (int k = 0; k < 4; k++) {
            p[k] = (float)exp((double)__fsub_rn(z[k], m));
            sum = __fadd_rn(sum, p[k]);
        }
        float s_k   = __fdiv_rn(p[kb], sum);
        float attn1 = __fadd_rn(__fsub_rn(1.0f, s_k), s_k);  // forward value of attn at argmax
        float Qp    = (float)((1 << (kb + 2)) - 1);
        float rQp   = __fmul_rn(attn1, Qp);
        float r_al  = __fmul_rn(attn1, alpha_a[kb]);
        float g_a   = __fdiv_rn(1.0f, __fsqrt_rn(__fmul_rn(401408.0f, rQp)));
        float ta    = __fmul_rn(r_al, g_a);
        float a     = __fadd_rn(__fsub_rn(r_al, ta), ta);
        float Qpw   = (float)((1 << (kb + 1)) - 1);
        float g_w   = __fdiv_rn(1.0f, __fsqrt_rn(__fmul_rn(589824.0f, Qpw)));
        float tw    = __fmul_rn(alpha_w[kb], g_w);
        float aw    = __fadd_rn(__fsub_rn(alpha_w[kb], tw), tw);
        params[b * 8 + 0] = __int_as_float(kb);
        params[b * 8 + 1] = a;
        params[b * 8 + 2] = rQp;
        params[b * 8 + 3] = attn1;
        params[b * 8 + 4] = __fmul_rn(a, aw);
    }
}

// ---------------- weight quant -> swizzled bf16 levels [k][tap][cb][o][c'] ----------------
__global__ void wq_kernel(const float* __restrict__ w, const float* __restrict__ alpha_w,
                          unsigned short* __restrict__ wlev) {
    int idx = blockIdx.x * 256 + threadIdx.x; // 589824 = 4*128*128*9
    int tap = idx % 9; int rest = idx / 9;
    int c = rest % 128; rest /= 128;
    int o = rest % 128; int k = rest / 128;
    float Qpw = (float)((1 << (k + 1)) - 1);
    float Qnw = -(float)(1 << (k + 1));
    float g_w = __fdiv_rn(1.0f, __fsqrt_rn(__fmul_rn(589824.0f, Qpw)));
    float tw  = __fmul_rn(alpha_w[k], g_w);
    float aw  = __fadd_rn(__fsub_rn(alpha_w[k], tw), tw);
    float lv  = rintf(fminf(fmaxf(__fdiv_rn(w[idx], aw), Qnw), Qpw));
    size_t dst = ((((size_t)k * 9 + tap) * 4 + (c >> 5)) * 128 + o) * 32 + (c & 31);
    wlev[dst] = f2bf_bits(lv);
}

// ---------------- x quant + transpose -> bf16 levels [b][p][c] ----------------
__global__ void xq_kernel(const float* __restrict__ x, const float* __restrict__ params,
                          unsigned short* __restrict__ xlev) {
    __shared__ unsigned short lds[64 * 136]; // 64 pixels x 128 c, padded rows (272B, 16B-aligned)
    int b = blockIdx.y, tile = blockIdx.x;
    int p0 = tile * 64;
    float a = params[b * 8 + 1], rQp = params[b * 8 + 2];
    const float* xb = x + (size_t)b * 401408;
    int t = threadIdx.x;
    int cc = t >> 4;          // 0..15
    int p4 = (t & 15) * 4;    // 0..60
    for (int j = 0; j < 8; j++) {
        int c = cc * 8 + j;
        float4 v = *(const float4*)(xb + (size_t)c * HW + p0 + p4);
        float q0 = rintf(fminf(fmaxf(__fdiv_rn(v.x, a), 0.0f), rQp));
        float q1 = rintf(fminf(fmaxf(__fdiv_rn(v.y, a), 0.0f), rQp));
        float q2 = rintf(fminf(fmaxf(__fdiv_rn(v.z, a), 0.0f), rQp));
        float q3 = rintf(fminf(fmaxf(__fdiv_rn(v.w, a), 0.0f), rQp));
        lds[(p4 + 0) * 136 + c] = f2bf_bits(q0);
        lds[(p4 + 1) * 136 + c] = f2bf_bits(q1);
        lds[(p4 + 2) * 136 + c] = f2bf_bits(q2);
        lds[(p4 + 3) * 136 + c] = f2bf_bits(q3);
    }
    __syncthreads();
    int p = t >> 2, seg = t & 3;
    u64x2* dst = (u64x2*)(xlev + (size_t)b * 401408 + (size_t)(p0 + p) * 128 + seg * 32);
    const unsigned short* s = &lds[p * 136 + seg * 32];
    dst[0] = *(const u64x2*)(s);
    dst[1] = *(const u64x2*)(s + 8);
    dst[2] = *(const u64x2*)(s + 16);
    dst[3] = *(const u64x2*)(s + 24);
}

// ---------------- conv: implicit GEMM, 128x128 block tile, bf16 MFMA on integer levels ----------------
__launch_bounds__(256)
__global__ void conv_kernel(const unsigned short* __restrict__ xlev,
                            const unsigned short* __restrict__ wlev,
                            const float* __restrict__ params,
                            const float* __restrict__ bias,
                            float* __restrict__ out) {
    __shared__ unsigned short Alds[128 * 40]; // weights [o][c'], rows 80B (16B-aligned, conflict-free b128)
    __shared__ unsigned short Blds[128 * 40]; // x levels [p][c']
    int b = blockIdx.y;
    int tile = blockIdx.x;  // 0..24 (25 tiles of 128 pixels; last half-masked)
    int p0 = tile * 128;
    int kb = __float_as_int(params[b * 8 + 0]);
    float scale = params[b * 8 + 4], attn1 = params[b * 8 + 3];
    const unsigned short* xb = xlev + (size_t)b * 401408;
    const unsigned short* wb = wlev + (size_t)kb * 9 * 4 * 4096;
    int tid = threadIdx.x;
    int lane = tid & 63, wv = tid >> 6;
    int wm = wv & 1, wn = wv >> 1;
    int q = lane >> 4, l16 = lane & 15;

    f32x4 acc[4][4] = {};

    int c8  = (tid & 3) * 8;
    int pB0 = tid >> 2, pB1 = (tid >> 2) + 64;
    int pf0 = p0 + pB0, pf1 = p0 + pB1;
    int h0 = pf0 / 56, w0 = pf0 - h0 * 56;
    int h1 = pf1 / 56, w1 = pf1 - h1 * 56;

    for (int t9 = 0; t9 < 9; t9++) {
        int dh = t9 / 3 - 1, dw = t9 % 3 - 1;
        int shift = dh * 56 + dw;
        bool v0 = (pf0 < 3136) && ((unsigned)(h0 + dh) < 56u) && ((unsigned)(w0 + dw) < 56u);
        bool v1 = (pf1 < 3136) && ((unsigned)(h1 + dh) < 56u) && ((unsigned)(w1 + dw) < 56u);
        const unsigned short* wt = wb + t9 * 4 * 4096;
        for (int cb = 0; cb < 4; cb++) {
            // stage A (8KB): [o][c'] already pre-swizzled contiguous in global
            const u64x2* ga = (const u64x2*)(wt + cb * 4096);
            u64x2 va0 = ga[tid];
            u64x2 va1 = ga[tid + 256];
            // stage B (8KB) with zero-padding mask
            int c0 = cb * 32;
            u64x2 vb0 = {0, 0}, vb1 = {0, 0};
            if (v0) vb0 = *(const u64x2*)(xb + (size_t)(pf0 + shift) * 128 + c0 + c8);
            if (v1) vb1 = *(const u64x2*)(xb + (size_t)(pf1 + shift) * 128 + c0 + c8);
            *(u64x2*)(&Alds[(tid >> 2) * 40 + c8])        = va0;
            *(u64x2*)(&Alds[((tid >> 2) + 64) * 40 + c8]) = va1;
            *(u64x2*)(&Blds[pB0 * 40 + c8]) = vb0;
            *(u64x2*)(&Blds[pB1 * 40 + c8]) = vb1;
            __syncthreads();
            s16x8 af[4], bf[4];
            for (int mt = 0; mt < 4; mt++)
                af[mt] = *(const s16x8*)(&Alds[(wm * 64 + mt * 16 + l16) * 40 + q * 8]);
            for (int nt = 0; nt < 4; nt++)
                bf[nt] = *(const s16x8*)(&Blds[(wn * 64 + nt * 16 + l16) * 40 + q * 8]);
            for (int mt = 0; mt < 4; mt++)
                for (int nt = 0; nt < 4; nt++)
                    acc[mt][nt] = __builtin_amdgcn_mfma_f32_16x16x32_bf16(
                        __builtin_bit_cast(bf16x8, af[mt]),
                        __builtin_bit_cast(bf16x8, bf[nt]),
                        acc[mt][nt], 0, 0, 0);
            __syncthreads();
        }
    }
    // epilogue: out = fl(scale*acc_int) + fl(attn1*bias)
    const float* bias_k = bias + kb * 128;
    for (int mt = 0; mt < 4; mt++) {
        for (int r = 0; r < 4; r++) {
            int o = wm * 64 + mt * 16 + q * 4 + r;
            float bt = __fmul_rn(attn1, bias_k[o]);
            float* orow = out + ((size_t)b * 128 + o) * 3136;
            for (int nt = 0; nt < 4; nt++) {
                int pf = p0 + wn * 64 + nt * 16 + l16;
                if (pf < 3136)
                    orow[pf] = __fadd_rn(__fmul_rn(scale, acc[mt][nt][r]), bt);
            }
        }
    }
}

extern "C" void kernel_launch(void* const* d_in, const int* in_sizes, int n_in,
                              void* d_out, int out_size, void* d_ws, size_t ws_size,
                              hipStream_t stream) {
    const float* x        = (const float*)d_in[0];
    const float* fc1_w    = (const float*)d_in[1];
    const float* fc2_w    = (const float*)d_in[2];
    const float* fc2_b    = (const float*)d_in[3];
    const float* alpha_w  = (const float*)d_in[4];
    const float* alpha_a  = (const float*)d_in[5];
    const float* weight   = (const float*)d_in[6];
    const float* bias     = (const float*)d_in[7];
    float* out = (float*)d_out;

    char* ws = (char*)d_ws;
    unsigned short* xlev = (unsigned short*)(ws);
    unsigned short* wlev = (unsigned short*)(ws + WLEV_OFF);
    double* pooled       = (double*)(ws + POOL_OFF);
    float* par           = (float*)(ws + PAR_OFF);

    hipLaunchKernelGGL(pool_kernel, dim3(2048), dim3(256), 0, stream, x, pooled);
    hipLaunchKernelGGL(gate_kernel, dim3(64), dim3(64), 0, stream,
                       pooled, fc1_w, fc2_w, fc2_b, alpha_w, alpha_a, par, out + 25690112);
    hipLaunchKernelGGL(wq_kernel, dim3(2304), dim3(256), 0, stream, weight, alpha_w, wlev);
    hipLaunchKernelGGL(xq_kernel, dim3(49, 64), dim3(256), 0, stream, x, par, xlev);
    hipLaunchKernelGGL(conv_kernel, dim3(25, 64), dim3(256), 0, stream, xlev, wlev, par, bias, out);
}

// Round 3
// 296.903 us; speedup vs baseline: 1.6915x; 1.0590x over previous
//
#include <hip/hip_runtime.h>

#define HW 3136

typedef __attribute__((ext_vector_type(4))) float f32x4;
typedef __attribute__((ext_vector_type(8))) short s16x8;
typedef __attribute__((ext_vector_type(8))) __bf16 bf16x8;
typedef unsigned long long ull;
typedef __attribute__((ext_vector_type(2))) ull u64x2;

// ws layout (bytes)
#define XLEV_BYTES (25690112UL * 2UL)
#define WLEV_OFF   XLEV_BYTES
#define WLEV_BYTES (589824UL * 2UL)
#define POOL_OFF   (WLEV_OFF + WLEV_BYTES)
#define POOL_BYTES (8192UL * 8UL)
#define PAR_OFF    (POOL_OFF + POOL_BYTES)
#define ZP_OFF     (PAR_OFF + 4096UL)

__device__ __forceinline__ unsigned short f2bf_bits(float f) {
    // values are exact small integers -> truncation of top 16 bits is exact
    return (unsigned short)(__float_as_uint(f) >> 16);
}

__device__ __forceinline__ void glds16(const void* g, void* l) {
    __builtin_amdgcn_global_load_lds((const __attribute__((address_space(1))) void*)g,
                                     (__attribute__((address_space(3))) void*)l, 16, 0, 0);
}

// ---------------- pool: pooled[b][c] = mean_{h,w} x  (f64 accumulate) ----------------
__global__ void pool_kernel(const float* __restrict__ x, double* __restrict__ pooled) {
    int row = blockIdx.x * 4 + (threadIdx.x >> 6); // (b*128+c), 8192 rows
    int lane = threadIdx.x & 63;
    const float4* xr = (const float4*)(x + (size_t)row * HW);
    double s = 0.0;
    for (int i = lane; i < 784; i += 64) {
        float4 v = xr[i];
        s += (double)v.x + (double)v.y + (double)v.z + (double)v.w;
    }
    for (int off = 32; off; off >>= 1) s += __shfl_down(s, off, 64);
    if (lane == 0) pooled[row] = s / 3136.0;
}

// ---------------- gate: 64 blocks (one per batch), 64 threads ----------------
__global__ void gate_kernel(const double* __restrict__ pooled,
                            const float* __restrict__ fc1, const float* __restrict__ fc2,
                            const float* __restrict__ fc2b, const float* __restrict__ alpha_w,
                            const float* __restrict__ alpha_a,
                            float* __restrict__ params, float* __restrict__ raw_out) {
    int b = blockIdx.x;
    int t = threadIdx.x; // 64
    __shared__ double pl[128];
    __shared__ double hsh[33];
    __shared__ float rawsh[4];
    pl[t]      = pooled[b * 128 + t];
    pl[t + 64] = pooled[b * 128 + 64 + t];
    __syncthreads();
    if (t < 33) {
        double s = 0.0;
        for (int c = 0; c < 128; c++) s += pl[c] * (double)fc1[t * 128 + c];
        hsh[t] = s > 0.0 ? s : 0.0;
    }
    __syncthreads();
    if (t < 4) {
        double s = (double)fc2b[t];
        for (int j = 0; j < 33; j++) s += hsh[j] * (double)fc2[t * 33 + j];
        float r = (float)s;
        rawsh[t] = r;
        raw_out[b * 4 + t] = r;
    }
    __syncthreads();
    if (t == 0) {
        float raw[4];
        for (int k = 0; k < 4; k++) raw[k] = rawsh[k];
        int kb = 0; float mx = raw[0];
        for (int k = 1; k < 4; k++) if (raw[k] > mx) { mx = raw[k]; kb = k; }
        float z[4], m = -1e30f;
        for (int k = 0; k < 4; k++) { z[k] = __fdiv_rn(raw[k], 34.0f); m = fmaxf(m, z[k]); }
        float p[4], sum = 0.0f;
        for (int k = 0; k < 4; k++) {
            p[k] = (float)exp((double)__fsub_rn(z[k], m));
            sum = __fadd_rn(sum, p[k]);
        }
        float s_k   = __fdiv_rn(p[kb], sum);
        float attn1 = __fadd_rn(__fsub_rn(1.0f, s_k), s_k);
        float Qp    = (float)((1 << (kb + 2)) - 1);
        float rQp   = __fmul_rn(attn1, Qp);
        float r_al  = __fmul_rn(attn1, alpha_a[kb]);
        float g_a   = __fdiv_rn(1.0f, __fsqrt_rn(__fmul_rn(401408.0f, rQp)));
        float ta    = __fmul_rn(r_al, g_a);
        float a     = __fadd_rn(__fsub_rn(r_al, ta), ta);
        float Qpw   = (float)((1 << (kb + 1)) - 1);
        float g_w   = __fdiv_rn(1.0f, __fsqrt_rn(__fmul_rn(589824.0f, Qpw)));
        float tw    = __fmul_rn(alpha_w[kb], g_w);
        float aw    = __fadd_rn(__fsub_rn(alpha_w[kb], tw), tw);
        params[b * 8 + 0] = __int_as_float(kb);
        params[b * 8 + 1] = a;
        params[b * 8 + 2] = rQp;
        params[b * 8 + 3] = attn1;
        params[b * 8 + 4] = __fmul_rn(a, aw);
    }
}

// ---------------- weight quant -> wlev [k][tap][cb][o][c'32], coalesced 16B stores ----------------
__global__ void wq_kernel(const float* __restrict__ w, const float* __restrict__ alpha_w,
                          unsigned short* __restrict__ wlev) {
    int id = blockIdx.x * 256 + threadIdx.x;  // 73728 ids, each -> 8 c' elems
    int cg = id & 3;
    int o  = (id >> 2) & 127;
    int cb = (id >> 9) & 3;
    int rest = id >> 11;            // k*9 + tap
    int tap = rest % 9, k = rest / 9;
    float Qpw = (float)((1 << (k + 1)) - 1);
    float Qnw = -(float)(1 << (k + 1));
    float g_w = __fdiv_rn(1.0f, __fsqrt_rn(__fmul_rn(589824.0f, Qpw)));
    float tw  = __fmul_rn(alpha_w[k], g_w);
    float aw  = __fadd_rn(__fsub_rn(alpha_w[k], tw), tw);
    const float* wsrc = w + ((size_t)(k * 128 + o) * 128 + cb * 32 + cg * 8) * 9 + tap;
    s16x8 outv;
    for (int j = 0; j < 8; j++) {
        float lv = rintf(fminf(fmaxf(__fdiv_rn(wsrc[j * 9], aw), Qnw), Qpw));
        outv[j] = (short)f2bf_bits(lv);
    }
    *(s16x8*)(wlev + (size_t)id * 8) = outv;
}

// ---------------- x quant + transpose -> bf16 levels [b][cb][p][c'32] ----------------
__global__ void xq_kernel(const float* __restrict__ x, const float* __restrict__ params,
                          unsigned short* __restrict__ xlev) {
    __shared__ unsigned short lds[64 * 136];
    int b = blockIdx.y, tile = blockIdx.x;
    int p0 = tile * 64;
    float a = params[b * 8 + 1], rQp = params[b * 8 + 2];
    const float* xb = x + (size_t)b * 401408;
    int t = threadIdx.x;
    int cc = t >> 4;          // 0..15
    int p4 = (t & 15) * 4;    // 0..60
    for (int j = 0; j < 8; j++) {
        int c = cc * 8 + j;
        float4 v = *(const float4*)(xb + (size_t)c * HW + p0 + p4);
        float q0 = rintf(fminf(fmaxf(__fdiv_rn(v.x, a), 0.0f), rQp));
        float q1 = rintf(fminf(fmaxf(__fdiv_rn(v.y, a), 0.0f), rQp));
        float q2 = rintf(fminf(fmaxf(__fdiv_rn(v.z, a), 0.0f), rQp));
        float q3 = rintf(fminf(fmaxf(__fdiv_rn(v.w, a), 0.0f), rQp));
        lds[(p4 + 0) * 136 + c] = f2bf_bits(q0);
        lds[(p4 + 1) * 136 + c] = f2bf_bits(q1);
        lds[(p4 + 2) * 136 + c] = f2bf_bits(q2);
        lds[(p4 + 3) * 136 + c] = f2bf_bits(q3);
    }
    __syncthreads();
    int p = t >> 2, seg = t & 3;
    const unsigned short* s = &lds[p * 136];
    unsigned short* dstb = xlev + (size_t)b * 4 * 100352 + (size_t)(p0 + p) * 32 + seg * 8;
    for (int cb = 0; cb < 4; cb++) {
        *(u64x2*)(dstb + (size_t)cb * 100352) = *(const u64x2*)(s + cb * 32 + seg * 8);
    }
}

// ---------------- conv: implicit GEMM, 128x128 tile, global_load_lds staging ----------------
__launch_bounds__(256)
__global__ void conv_kernel(const unsigned short* __restrict__ xlev,
                            const unsigned short* __restrict__ wlev,
                            const float* __restrict__ params,
                            const float* __restrict__ bias,
                            const unsigned short* __restrict__ zp,
                            float* __restrict__ out) {
    __shared__ unsigned short Alds[128 * 32]; // weights [o][c'32], 64B rows (m97 layout)
    __shared__ unsigned short Blds[128 * 32]; // pixels  [p][c'32]
    // XCD-aware swizzle: all 25 tiles of one b land on one XCD (xlev plane 803KB << 4MB L2)
    int lid = blockIdx.x + blockIdx.y * 25;
    int xcd = lid & 7, slot = lid >> 3;
    int b = xcd * 8 + slot / 25;
    int tile = slot % 25;
    int p0 = tile * 128;
    int kb = __float_as_int(params[b * 8 + 0]);
    float scale = params[b * 8 + 4], attn1 = params[b * 8 + 3];
    const unsigned short* xb = xlev + (size_t)b * 4 * 100352; // [cb][p][32]
    const unsigned short* wb = wlev + (size_t)kb * 9 * 4 * 4096;
    int tid = threadIdx.x;
    int lane = tid & 63, wv = tid >> 6;
    int wm = wv & 1, wn = wv >> 1;
    int q = lane >> 4, l16 = lane & 15;

    f32x4 acc[4][4] = {};

    int row0 = tid >> 2;              // B row this thread stages (and +64)
    int segs = (tid & 3) * 8;         // short offset within 32-elem row
    int pf0 = p0 + row0, pf1 = pf0 + 64;
    int h0 = pf0 / 56, w0 = pf0 - h0 * 56;
    int h1 = pf1 / 56, w1 = pf1 - h1 * 56;

    // LDS dest bases: lane writes base + lane*16B; thread t covers bytes t*16 and t*16+4096
    unsigned short* ldsA0 = Alds + wv * 512;
    unsigned short* ldsA1 = Alds + 2048 + wv * 512;
    unsigned short* ldsB0 = Blds + wv * 512;
    unsigned short* ldsB1 = Blds + 2048 + wv * 512;
    const unsigned short* zpp = zp + segs;

    for (int t9 = 0; t9 < 9; t9++) {
        int dh = t9 / 3 - 1, dw = t9 % 3 - 1;
        int shift = dh * 56 + dw;
        bool v0 = (pf0 < 3136) && ((unsigned)(h0 + dh) < 56u) && ((unsigned)(w0 + dw) < 56u);
        bool v1 = (pf1 < 3136) && ((unsigned)(h1 + dh) < 56u) && ((unsigned)(w1 + dw) < 56u);
        const unsigned short* wt = wb + t9 * 4 * 4096;
        const unsigned short* xr0 = xb + (size_t)(pf0 + shift) * 32 + segs;
        const unsigned short* xr1 = xb + (size_t)(pf1 + shift) * 32 + segs;
        for (int cb = 0; cb < 4; cb++) {
            const unsigned short* sA = wt + cb * 4096 + tid * 8;
            const unsigned short* sB0 = v0 ? xr0 + cb * 100352 : zpp;
            const unsigned short* sB1 = v1 ? xr1 + cb * 100352 : zpp;
            glds16(sA, ldsA0);
            glds16(sA + 2048, ldsA1);
            glds16(sB0, ldsB0);
            glds16(sB1, ldsB1);
            __syncthreads();
            s16x8 af[4], bf[4];
            for (int mt = 0; mt < 4; mt++)
                af[mt] = *(const s16x8*)(&Alds[(wm * 64 + mt * 16 + l16) * 32 + q * 8]);
            for (int nt = 0; nt < 4; nt++)
                bf[nt] = *(const s16x8*)(&Blds[(wn * 64 + nt * 16 + l16) * 32 + q * 8]);
            for (int mt = 0; mt < 4; mt++)
                for (int nt = 0; nt < 4; nt++)
                    acc[mt][nt] = __builtin_amdgcn_mfma_f32_16x16x32_bf16(
                        __builtin_bit_cast(bf16x8, af[mt]),
                        __builtin_bit_cast(bf16x8, bf[nt]),
                        acc[mt][nt], 0, 0, 0);
            __syncthreads();
        }
    }
    // epilogue: out = fl(scale*acc_int) + fl(attn1*bias)
    const float* bias_k = bias + kb * 128;
    for (int mt = 0; mt < 4; mt++) {
        for (int r = 0; r < 4; r++) {
            int o = wm * 64 + mt * 16 + q * 4 + r;
            float bt = __fmul_rn(attn1, bias_k[o]);
            float* orow = out + ((size_t)b * 128 + o) * 3136;
            for (int nt = 0; nt < 4; nt++) {
                int pf = p0 + wn * 64 + nt * 16 + l16;
                if (pf < 3136)
                    orow[pf] = __fadd_rn(__fmul_rn(scale, acc[mt][nt][r]), bt);
            }
        }
    }
}

extern "C" void kernel_launch(void* const* d_in, const int* in_sizes, int n_in,
                              void* d_out, int out_size, void* d_ws, size_t ws_size,
                              hipStream_t stream) {
    const float* x        = (const float*)d_in[0];
    const float* fc1_w    = (const float*)d_in[1];
    const float* fc2_w    = (const float*)d_in[2];
    const float* fc2_b    = (const float*)d_in[3];
    const float* alpha_w  = (const float*)d_in[4];
    const float* alpha_a  = (const float*)d_in[5];
    const float* weight   = (const float*)d_in[6];
    const float* bias     = (const float*)d_in[7];
    float* out = (float*)d_out;

    char* ws = (char*)d_ws;
    unsigned short* xlev = (unsigned short*)(ws);
    unsigned short* wlev = (unsigned short*)(ws + WLEV_OFF);
    double* pooled       = (double*)(ws + POOL_OFF);
    float* par           = (float*)(ws + PAR_OFF);
    unsigned short* zp   = (unsigned short*)(ws + ZP_OFF);

    hipMemsetAsync(zp, 0, 256, stream);
    hipLaunchKernelGGL(pool_kernel, dim3(2048), dim3(256), 0, stream, x, pooled);
    hipLaunchKernelGGL(gate_kernel, dim3(64), dim3(64), 0, stream,
                       pooled, fc1_w, fc2_w, fc2_b, alpha_w, alpha_a, par, out + 25690112);
    hipLaunchKernelGGL(wq_kernel, dim3(288), dim3(256), 0, stream, weight, alpha_w, wlev);
    hipLaunchKernelGGL(xq_kernel, dim3(49, 64), dim3(256), 0, stream, x, par, xlev);
    hipLaunchKernelGGL(conv_kernel, dim3(25, 64), dim3(256), 0, stream, xlev, wlev, par, bias, zp, out);
}